// Round 12
// baseline (674.295 us; speedup 1.0000x reference)
//
#include <hip/hip_runtime.h>
#include <math.h>

#define NN 100000
#define EE 640000
#define DD 128
#define CC 40
#define FIXS 4194304.0f  // 2^22 fixed-point scale for deg

typedef __bf16 bf16x8 __attribute__((ext_vector_type(8)));
typedef float f32x4 __attribute__((ext_vector_type(4)));
typedef unsigned short us8 __attribute__((ext_vector_type(8)));

__device__ inline unsigned short f2b(float f) {
    union { float f; unsigned u; } v; v.f = f;
    unsigned u = v.u;
    return (unsigned short)((u + 0x7FFFu + ((u >> 16) & 1u)) >> 16);
}
__device__ inline float b2f(unsigned short b) {
    union { unsigned u; float f; } v; v.u = ((unsigned)b) << 16;
    return v.f;
}

// ---------------- graph preprocessing ----------------

__global__ __launch_bounds__(256) void k_edge1(const int* __restrict__ dst,
                                               const float* __restrict__ w,
                                               unsigned long long* __restrict__ degcnt,
                                               int* __restrict__ pos) {
    int e = blockIdx.x * 256 + threadIdx.x;
    if (e < EE) {
        int d = dst[e];
        unsigned long long pk =
            ((unsigned long long)(unsigned)(w[e] * FIXS) << 32) | 1ull;
        unsigned long long old = atomicAdd(&degcnt[d], pk);
        pos[e] = (int)(old & 0xffffffffull);
    }
}

// ---- degree counting sort: hist -> scan -> rank-scatter ----
// gbin[0..31] = histogram/binStart, gbin[32..63] = fill counters (pre-zeroed)

__global__ __launch_bounds__(256) void k_dhist(const unsigned long long* __restrict__ degcnt,
                                               int* __restrict__ gbin) {
    __shared__ int lh[32];
    int t = threadIdx.x;
    if (t < 32) lh[t] = 0;
    __syncthreads();
    int i = blockIdx.x * 256 + t;
    if (i < NN) {
        int d = (int)(degcnt[i] & 0xffffffffull);
        d = d < 31 ? d : 31;
        atomicAdd(&lh[d], 1);
    }
    __syncthreads();
    if (t < 32 && lh[t]) atomicAdd(&gbin[t], lh[t]);
}

__global__ __launch_bounds__(64) void k_dscan(int* __restrict__ gbin) {
    if (threadIdx.x == 0) {
        int run = 0;
        for (int b = 0; b < 32; ++b) { int c = gbin[b]; gbin[b] = run; run += c; }
    }
}

__global__ __launch_bounds__(256) void k_dscatter(const unsigned long long* __restrict__ degcnt,
                                                  int* __restrict__ gbin,
                                                  int* __restrict__ order) {
    __shared__ int lh[32];
    __shared__ int lbase[32];
    int t = threadIdx.x;
    if (t < 32) lh[t] = 0;
    __syncthreads();
    int i = blockIdx.x * 256 + t;
    int d = 0, r = 0;
    bool ok = i < NN;
    if (ok) {
        d = (int)(degcnt[i] & 0xffffffffull);
        d = d < 31 ? d : 31;
        r = atomicAdd(&lh[d], 1);
    }
    __syncthreads();
    if (t < 32) lbase[t] = lh[t] ? atomicAdd(&gbin[32 + t], lh[t]) : 0;
    __syncthreads();
    if (ok) order[gbin[d] + lbase[d] + r] = i;
}

// blocks 0..97: scan over cnt + dinv; blocks 98+: weight prep (independent work)
__global__ __launch_bounds__(256) void k_scan1p(const unsigned long long* __restrict__ degcnt,
                                                float* __restrict__ dinv,
                                                int* __restrict__ out,
                                                int* __restrict__ partial,
                                                const float* __restrict__ Wb,
                                                const float* __restrict__ Wf,
                                                unsigned short* __restrict__ WT,
                                                unsigned short* __restrict__ WfT) {
    int t = threadIdx.x;
    if (blockIdx.x >= 98) {
        int idx = (blockIdx.x - 98) * 256 + t;
        if (idx < 8 * DD * DD) {
            int m = idx >> 14;
            int n = (idx >> 7) & 127;
            int k = idx & 127;
            WT[idx] = f2b(Wb[(size_t)m * DD * DD + (size_t)k * DD + n]);
        } else {
            int j = idx - 8 * DD * DD;
            if (j < 64 * DD) {
                int n = j >> 7;
                int k = j & 127;
                WfT[j] = (n < CC) ? f2b(Wf[(size_t)k * CC + n]) : 0;
            }
        }
        return;
    }
    __shared__ int lds[256];
    int base = blockIdx.x * 1024 + t * 4;
    int v[4]; int s = 0;
    #pragma unroll
    for (int j = 0; j < 4; ++j) {
        int idx = base + j;
        unsigned long long dc = (idx < NN) ? degcnt[idx] : 0ull;
        v[j] = (int)(dc & 0xffffffffull);
        s += v[j];
        if (idx < NN)
            dinv[idx] = rsqrtf((float)(unsigned)(dc >> 32) * (1.0f / FIXS) + 1.0f);
    }
    lds[t] = s;
    __syncthreads();
    for (int off = 1; off < 256; off <<= 1) {
        int x = lds[t];
        int y = (t >= off) ? lds[t - off] : 0;
        __syncthreads();
        lds[t] = x + y;
        __syncthreads();
    }
    int excl = lds[t] - s;
    if (t == 255) partial[blockIdx.x] = lds[255];
    int run = excl;
    #pragma unroll
    for (int j = 0; j < 4; ++j) {
        int idx = base + j;
        if (idx < NN) out[idx] = run;
        run += v[j];
    }
}

// scan3 with inline scan-of-partials
__global__ __launch_bounds__(256) void k_scan3(int* __restrict__ rp,
                                               const int* __restrict__ partial) {
    __shared__ int lds[128];
    int t = threadIdx.x;
    if (t < 128) lds[t] = (t < 98) ? partial[t] : 0;
    __syncthreads();
    for (int off = 1; off < 128; off <<= 1) {
        int x = (t < 128) ? lds[t] : 0;
        int y = (t >= off && t < 128) ? lds[t - off] : 0;
        __syncthreads();
        if (t < 128) lds[t] = x + y;
        __syncthreads();
    }
    int i = blockIdx.x * 256 + t;
    if (i < NN) {
        int c = i >> 10;
        int add = c ? lds[c - 1] : 0;
        rp[i] += add;
    }
    if (i == 0) rp[NN] = EE;
}

// atomic-free scatter; packs (col, val) into int2
__global__ __launch_bounds__(256) void k_scatter(const int* __restrict__ src,
                                                 const int* __restrict__ dst,
                                                 const float* __restrict__ w,
                                                 const float* __restrict__ dinv,
                                                 const int* __restrict__ rp,
                                                 const int* __restrict__ pos,
                                                 int2* __restrict__ cvp) {
    int e = blockIdx.x * 256 + threadIdx.x;
    if (e < EE) {
        int s = src[e], d = dst[e];
        int p = rp[d] + pos[e];
        int2 cv;
        cv.x = s;
        cv.y = __float_as_int(dinv[s] * w[e] * dinv[d]);
        cvp[p] = cv;
    }
}

// fp32 x -> bf16 Abf
__global__ __launch_bounds__(256) void k_x2bf(const float* __restrict__ x,
                                              unsigned short* __restrict__ Abf) {
    int idx = blockIdx.x * 256 + threadIdx.x;
    if (idx >= NN * DD / 4) return;
    float4 v = ((const float4*)x)[idx];
    ushort4 r;
    r.x = f2b(v.x); r.y = f2b(v.y); r.z = f2b(v.z); r.w = f2b(v.w);
    ((ushort4*)Abf)[idx] = r;
}

// ---------------- MFMA epilogue: within-wave LDS transpose -> coalesced us8 stores ----

#define MM_EPILOGUE_128(H_)                                                  \
    {                                                                        \
        _Pragma("unroll")                                                    \
        for (int n = 0; n < 8; ++n) {                                        \
            _Pragma("unroll")                                                \
            for (int v = 0; v < 4; ++v)                                      \
                tb[wid][g * 4 + v][n * 16 + sl] = f2b(acc[n][v]);            \
        }                                                                    \
        _Pragma("unroll")                                                    \
        for (int c4 = 0; c4 < 4; ++c4) {                                     \
            int chunk = c4 * 64 + lane;                                      \
            int row = chunk >> 4, seg = chunk & 15;                          \
            int grow = r0 + row;                                             \
            if (grow < NN)                                                   \
                *(us8*)(H_ + (size_t)grow * DD + seg * 8) =                  \
                    *(const us8*)(&tb[wid][row][seg * 8]);                   \
        }                                                                    \
    }

// ---------------- bf16 MFMA matmul: H[N,128] = X[N,128] @ W ----------------
__global__ __launch_bounds__(256) void k_mm_mfma(const unsigned short* __restrict__ X,
                                                 const unsigned short* __restrict__ WT,
                                                 unsigned short* __restrict__ H) {
    __shared__ unsigned short tb[4][16][136];
    int wid = threadIdx.x >> 6;
    int lane = threadIdx.x & 63;
    int r0 = blockIdx.x * 64 + wid * 16;
    int sl = lane & 15, g = lane >> 4;
    int arow = r0 + sl;
    if (arow >= NN) arow = NN - 1;

    f32x4 acc[8];
    #pragma unroll
    for (int n = 0; n < 8; ++n) acc[n] = (f32x4){0.f, 0.f, 0.f, 0.f};

    const bf16x8* xrow = (const bf16x8*)(X + (size_t)arow * DD);
    #pragma unroll
    for (int kc = 0; kc < 4; ++kc) {
        bf16x8 a = xrow[kc * 4 + g];
        #pragma unroll
        for (int n = 0; n < 8; ++n) {
            const bf16x8* wrow = (const bf16x8*)(WT + (size_t)(n * 16 + sl) * DD);
            bf16x8 b = wrow[kc * 4 + g];
            acc[n] = __builtin_amdgcn_mfma_f32_16x16x32_bf16(a, b, acc[n], 0, 0, 0);
        }
    }
    MM_EPILOGUE_128(H);
}

// projection into padded 64-col bf16
__global__ __launch_bounds__(256) void k_mm40b(const unsigned short* __restrict__ X,
                                               const unsigned short* __restrict__ WfT,
                                               unsigned short* __restrict__ H) {
    __shared__ unsigned short tb[4][16][72];
    int wid = threadIdx.x >> 6;
    int lane = threadIdx.x & 63;
    int r0 = blockIdx.x * 64 + wid * 16;
    int sl = lane & 15, g = lane >> 4;
    int arow = r0 + sl;
    if (arow >= NN) arow = NN - 1;

    f32x4 acc[4];
    #pragma unroll
    for (int n = 0; n < 4; ++n) acc[n] = (f32x4){0.f, 0.f, 0.f, 0.f};

    const bf16x8* xrow = (const bf16x8*)(X + (size_t)arow * DD);
    #pragma unroll
    for (int kc = 0; kc < 4; ++kc) {
        bf16x8 a = xrow[kc * 4 + g];
        #pragma unroll
        for (int n = 0; n < 4; ++n) {
            const bf16x8* wrow = (const bf16x8*)(WfT + (size_t)(n * 16 + sl) * DD);
            bf16x8 b = wrow[kc * 4 + g];
            acc[n] = __builtin_amdgcn_mfma_f32_16x16x32_bf16(a, b, acc[n], 0, 0, 0);
        }
    }
    #pragma unroll
    for (int n = 0; n < 4; ++n) {
        #pragma unroll
        for (int v = 0; v < 4; ++v)
            tb[wid][g * 4 + v][n * 16 + sl] = f2b(acc[n][v]);
    }
    #pragma unroll
    for (int c4 = 0; c4 < 2; ++c4) {
        int chunk = c4 * 64 + lane;
        int row = chunk >> 3, seg = chunk & 7;
        int grow = r0 + row;
        if (grow < NN)
            *(us8*)(H + (size_t)grow * 64 + seg * 8) =
                *(const us8*)(&tb[wid][row][seg * 8]);
    }
}

// ---------------- aggregation core (4-way unroll, packed col/val) ----------------

#define AGG_CORE(h_, node_, sl_, a_, STRIDE_)                               \
    {                                                                       \
        float dv = dinv[node_];                                             \
        float dv2 = dv * dv;                                                \
        us8 m_ = ((const us8*)(h_ + (size_t)node_ * STRIDE_))[sl_];         \
        _Pragma("unroll")                                                   \
        for (int j = 0; j < 8; ++j) a_[j] = dv2 * b2f(m_[j]);               \
        int e = rp[node_], end = rp[node_ + 1];                             \
        for (; e + 4 <= end; e += 4) {                                      \
            int2 c0 = cvp[e], c1 = cvp[e + 1], c2 = cvp[e + 2], c3 = cvp[e + 3]; \
            us8 q0 = ((const us8*)(h_ + (size_t)c0.x * STRIDE_))[sl_];      \
            us8 q1 = ((const us8*)(h_ + (size_t)c1.x * STRIDE_))[sl_];      \
            us8 q2 = ((const us8*)(h_ + (size_t)c2.x * STRIDE_))[sl_];      \
            us8 q3 = ((const us8*)(h_ + (size_t)c3.x * STRIDE_))[sl_];      \
            float v0 = __int_as_float(c0.y), v1 = __int_as_float(c1.y);     \
            float v2 = __int_as_float(c2.y), v3 = __int_as_float(c3.y);     \
            _Pragma("unroll")                                               \
            for (int j = 0; j < 8; ++j)                                     \
                a_[j] += (v0 * b2f(q0[j]) + v1 * b2f(q1[j]))                \
                       + (v2 * b2f(q2[j]) + v3 * b2f(q3[j]));               \
        }                                                                   \
        for (; e < end; ++e) {                                              \
            int2 c0 = cvp[e];                                               \
            us8 q0 = ((const us8*)(h_ + (size_t)c0.x * STRIDE_))[sl_];      \
            float v0 = __int_as_float(c0.y);                                \
            _Pragma("unroll")                                               \
            for (int j = 0; j < 8; ++j) a_[j] += v0 * b2f(q0[j]);           \
        }                                                                   \
    }

__global__ __launch_bounds__(256) void k_agg128(const unsigned short* __restrict__ h,
                                                const float* __restrict__ dinv,
                                                const int* __restrict__ rp,
                                                const int2* __restrict__ cvp,
                                                const int* __restrict__ order,
                                                const float* __restrict__ bias,
                                                unsigned short* __restrict__ outb) {
    int slot = blockIdx.x * 16 + (threadIdx.x >> 4);
    int sl = threadIdx.x & 15;
    if (slot >= NN) return;
    int node = order[slot];
    float a[8];
    AGG_CORE(h, node, sl, a, DD);
    float4 bz0 = ((const float4*)bias)[sl * 2];
    float4 bz1 = ((const float4*)bias)[sl * 2 + 1];
    float bb[8] = {bz0.x, bz0.y, bz0.z, bz0.w, bz1.x, bz1.y, bz1.z, bz1.w};
    us8 r;
    #pragma unroll
    for (int j = 0; j < 8; ++j) r[j] = f2b(fmaxf(a[j] + bb[j], 0.f));
    ((us8*)(outb + (size_t)node * DD))[sl] = r;
}

__global__ __launch_bounds__(256) void k_agg128_nr(const unsigned short* __restrict__ h,
                                                   const float* __restrict__ dinv,
                                                   const int* __restrict__ rp,
                                                   const int2* __restrict__ cvp,
                                                   const int* __restrict__ order,
                                                   const float* __restrict__ bias,
                                                   unsigned short* __restrict__ Abf) {
    int slot = blockIdx.x * 16 + (threadIdx.x >> 4);
    int sl = threadIdx.x & 15;
    if (slot >= NN) return;
    int node = order[slot];
    float a[8];
    AGG_CORE(h, node, sl, a, DD);
    float4 bz0 = ((const float4*)bias)[sl * 2];
    float4 bz1 = ((const float4*)bias)[sl * 2 + 1];
    float bb[8] = {bz0.x, bz0.y, bz0.z, bz0.w, bz1.x, bz1.y, bz1.z, bz1.w};
    float ss = 0.f;
    #pragma unroll
    for (int j = 0; j < 8; ++j) {
        a[j] = fmaxf(a[j] + bb[j], 0.f);
        ss += a[j] * a[j];
    }
    ss += __shfl_xor(ss, 1);
    ss += __shfl_xor(ss, 2);
    ss += __shfl_xor(ss, 4);
    ss += __shfl_xor(ss, 8);
    float sc = 1.0f / fmaxf(sqrtf(ss), 1e-12f);
    us8 oldb = ((const us8*)(Abf + (size_t)node * DD))[sl];
    us8 rb;
    #pragma unroll
    for (int j = 0; j < 8; ++j)
        rb[j] = f2b((a[j] * sc + b2f(oldb[j])) * 0.5f);
    ((us8*)(Abf + (size_t)node * DD))[sl] = rb;
}

__global__ __launch_bounds__(256) void k_agg_final(const unsigned short* __restrict__ h,
                                                   const float* __restrict__ dinv,
                                                   const int* __restrict__ rp,
                                                   const int2* __restrict__ cvp,
                                                   const int* __restrict__ order,
                                                   const float* __restrict__ bias,
                                                   float* __restrict__ out) {
    int slot = blockIdx.x * 32 + (threadIdx.x >> 3);
    int sl = threadIdx.x & 7;
    if (slot >= NN) return;
    int node = order[slot];
    float a[8];
    AGG_CORE(h, node, sl, a, 64);
    bool real = sl < 5;
    float vv[8];
    if (real) {
        float4 bz0 = ((const float4*)bias)[sl * 2];
        float4 bz1 = ((const float4*)bias)[sl * 2 + 1];
        float bb[8] = {bz0.x, bz0.y, bz0.z, bz0.w, bz1.x, bz1.y, bz1.z, bz1.w};
        #pragma unroll
        for (int j = 0; j < 8; ++j) vv[j] = a[j] + bb[j];
    } else {
        #pragma unroll
        for (int j = 0; j < 8; ++j) vv[j] = -3.0e38f;
    }
    float m = vv[0];
    #pragma unroll
    for (int j = 1; j < 8; ++j) m = fmaxf(m, vv[j]);
    m = fmaxf(m, __shfl_xor(m, 1));
    m = fmaxf(m, __shfl_xor(m, 2));
    m = fmaxf(m, __shfl_xor(m, 4));
    float s = 0.f;
    if (real) {
        #pragma unroll
        for (int j = 0; j < 8; ++j) s += expf(vv[j] - m);
    }
    s += __shfl_xor(s, 1);
    s += __shfl_xor(s, 2);
    s += __shfl_xor(s, 4);
    float ls = m + logf(s);
    if (real) {
        float4 o0 = {vv[0] - ls, vv[1] - ls, vv[2] - ls, vv[3] - ls};
        float4 o1 = {vv[4] - ls, vv[5] - ls, vv[6] - ls, vv[7] - ls};
        float* orow = out + (size_t)node * CC + sl * 8;
        *(float4*)(orow) = o0;
        *(float4*)(orow + 4) = o1;
    }
}

// ---------------- launch ----------------

extern "C" void kernel_launch(void* const* d_in, const int* in_sizes, int n_in,
                              void* d_out, int out_size, void* d_ws, size_t ws_size,
                              hipStream_t stream) {
    const float* x  = (const float*)d_in[0];
    const int*   ei = (const int*)d_in[1];
    const float* ew = (const float*)d_in[2];
    const float* Wb = (const float*)d_in[3];
    const float* bb = (const float*)d_in[4];
    const float* Wf = (const float*)d_in[5];
    const float* bf_ = (const float*)d_in[6];
    const int* src = ei;
    const int* dst = ei + EE;
    float* out = (float*)d_out;

    char* p = (char*)d_ws;
    unsigned short*     Abf    = (unsigned short*)p;     p += (size_t)NN * DD * 2;
    unsigned short*     Bbf    = (unsigned short*)p;     p += (size_t)NN * DD * 2;
    unsigned short*     Cbf    = (unsigned short*)p;     p += (size_t)NN * DD * 2;
    unsigned short*     H48    = (unsigned short*)p;     p += (size_t)NN * 64 * 2;
    unsigned short*     WT     = (unsigned short*)p;     p += (size_t)8 * DD * DD * 2;
    unsigned short*     WfT    = (unsigned short*)p;     p += (size_t)64 * DD * 2;
    unsigned long long* degcnt = (unsigned long long*)p; p += (size_t)NN * 8;
    int*   gbin = (int*)p;   p += 64 * 4;               // [0..31] binStart, [32..63] fill
    float* dinv = (float*)p; p += (size_t)NN * 4;
    int*   rp   = (int*)p;   p += (size_t)(NN + 1) * 4;
    int*   pos  = (int*)p;   p += (size_t)EE * 4;
    int2*  cvp  = (int2*)p;  p += (size_t)EE * 8;
    int*   order = (int*)p;  p += (size_t)NN * 4;
    int*   partial = (int*)p; p += 128 * 4;

    // zero degcnt + gbin in one memset (adjacent)
    hipMemsetAsync(degcnt, 0, (size_t)NN * 8 + 64 * 4, stream);

    k_edge1<<<(EE + 255) / 256, 256, 0, stream>>>(dst, ew, degcnt, pos);
    k_dhist<<<(NN + 255) / 256, 256, 0, stream>>>(degcnt, gbin);
    k_scan1p<<<98 + (8 * DD * DD + 64 * DD + 255) / 256, 256, 0, stream>>>(
        degcnt, dinv, rp, partial, Wb, Wf, WT, WfT);
    k_dscan<<<1, 64, 0, stream>>>(gbin);
    k_dscatter<<<(NN + 255) / 256, 256, 0, stream>>>(degcnt, gbin, order);
    k_scan3<<<(NN + 255) / 256, 256, 0, stream>>>(rp, partial);
    k_scatter<<<(EE + 255) / 256, 256, 0, stream>>>(src, dst, ew, dinv, rp, pos, cvp);
    k_x2bf<<<(NN * DD / 4 + 255) / 256, 256, 0, stream>>>(x, Abf);

    int gb = (NN + 63) / 64;
    k_mm_mfma<<<gb, 256, 0, stream>>>(Abf, WT, Bbf);
    for (int blk = 0; blk < 4; ++blk) {
        k_agg128<<<(NN + 15) / 16, 256, 0, stream>>>(Bbf, dinv, rp, cvp, order,
                                                     bb + (size_t)(2 * blk) * DD, Cbf);
        k_mm_mfma<<<gb, 256, 0, stream>>>(Cbf, WT + (size_t)(2 * blk + 1) * DD * DD, Bbf);
        k_agg128_nr<<<(NN + 15) / 16, 256, 0, stream>>>(Bbf, dinv, rp, cvp, order,
                                                        bb + (size_t)(2 * blk + 1) * DD, Abf);
        if (blk < 3)
            k_mm_mfma<<<gb, 256, 0, stream>>>(Abf, WT + (size_t)(2 * blk + 2) * DD * DD, Bbf);
    }
    k_mm40b<<<gb, 256, 0, stream>>>(Abf, WfT, H48);
    k_agg_final<<<(NN + 31) / 32, 256, 0, stream>>>(H48, dinv, rp, cvp, order, bf_, out);
}

// Round 13
// 636.871 us; speedup vs baseline: 1.0588x; 1.0588x over previous
//
#include <hip/hip_runtime.h>
#include <math.h>

#define NN 100000
#define EE 640000
#define DD 128
#define CC 40
#define FIXS 4194304.0f  // 2^22 fixed-point scale for deg

typedef __bf16 bf16x8 __attribute__((ext_vector_type(8)));
typedef float f32x4 __attribute__((ext_vector_type(4)));
typedef unsigned short us8 __attribute__((ext_vector_type(8)));

__device__ inline unsigned short f2b(float f) {
    union { float f; unsigned u; } v; v.f = f;
    unsigned u = v.u;
    return (unsigned short)((u + 0x7FFFu + ((u >> 16) & 1u)) >> 16);
}
__device__ inline float b2f(unsigned short b) {
    union { unsigned u; float f; } v; v.u = ((unsigned)b) << 16;
    return v.f;
}

// ---------------- graph preprocessing ----------------

__global__ __launch_bounds__(256) void k_edge1(const int* __restrict__ dst,
                                               const float* __restrict__ w,
                                               unsigned long long* __restrict__ degcnt,
                                               int* __restrict__ pos) {
    int e = blockIdx.x * 256 + threadIdx.x;
    if (e < EE) {
        int d = dst[e];
        unsigned long long pk =
            ((unsigned long long)(unsigned)(w[e] * FIXS) << 32) | 1ull;
        unsigned long long old = atomicAdd(&degcnt[d], pk);
        pos[e] = (int)(old & 0xffffffffull);
    }
}

// blocks 0..97: scan over cnt + dinv; blocks 98+: weight prep (independent work)
__global__ __launch_bounds__(256) void k_scan1p(const unsigned long long* __restrict__ degcnt,
                                                float* __restrict__ dinv,
                                                int* __restrict__ out,
                                                int* __restrict__ partial,
                                                const float* __restrict__ Wb,
                                                const float* __restrict__ Wf,
                                                unsigned short* __restrict__ WT,
                                                unsigned short* __restrict__ WfT) {
    int t = threadIdx.x;
    if (blockIdx.x >= 98) {
        int idx = (blockIdx.x - 98) * 256 + t;
        if (idx < 8 * DD * DD) {
            int m = idx >> 14;
            int n = (idx >> 7) & 127;
            int k = idx & 127;
            WT[idx] = f2b(Wb[(size_t)m * DD * DD + (size_t)k * DD + n]);
        } else {
            int j = idx - 8 * DD * DD;
            if (j < 64 * DD) {
                int n = j >> 7;
                int k = j & 127;
                WfT[j] = (n < CC) ? f2b(Wf[(size_t)k * CC + n]) : 0;
            }
        }
        return;
    }
    __shared__ int lds[256];
    int base = blockIdx.x * 1024 + t * 4;
    int v[4]; int s = 0;
    #pragma unroll
    for (int j = 0; j < 4; ++j) {
        int idx = base + j;
        unsigned long long dc = (idx < NN) ? degcnt[idx] : 0ull;
        v[j] = (int)(dc & 0xffffffffull);
        s += v[j];
        if (idx < NN)
            dinv[idx] = rsqrtf((float)(unsigned)(dc >> 32) * (1.0f / FIXS) + 1.0f);
    }
    lds[t] = s;
    __syncthreads();
    for (int off = 1; off < 256; off <<= 1) {
        int x = lds[t];
        int y = (t >= off) ? lds[t - off] : 0;
        __syncthreads();
        lds[t] = x + y;
        __syncthreads();
    }
    int excl = lds[t] - s;
    if (t == 255) partial[blockIdx.x] = lds[255];
    int run = excl;
    #pragma unroll
    for (int j = 0; j < 4; ++j) {
        int idx = base + j;
        if (idx < NN) out[idx] = run;
        run += v[j];
    }
}

// scan3 with inline scan-of-partials (absorbs old scan2)
__global__ __launch_bounds__(256) void k_scan3(int* __restrict__ rp,
                                               const int* __restrict__ partial) {
    __shared__ int lds[128];
    int t = threadIdx.x;
    if (t < 128) lds[t] = (t < 98) ? partial[t] : 0;
    __syncthreads();
    for (int off = 1; off < 128; off <<= 1) {
        int x = (t < 128) ? lds[t] : 0;
        int y = (t >= off && t < 128) ? lds[t - off] : 0;
        __syncthreads();
        if (t < 128) lds[t] = x + y;
        __syncthreads();
    }
    int i = blockIdx.x * 256 + t;
    if (i < NN) {
        int c = i >> 10;
        int add = c ? lds[c - 1] : 0;
        rp[i] += add;
    }
    if (i == 0) rp[NN] = EE;
}

// atomic-free scatter; packs (col, val) into int2
__global__ __launch_bounds__(256) void k_scatter(const int* __restrict__ src,
                                                 const int* __restrict__ dst,
                                                 const float* __restrict__ w,
                                                 const float* __restrict__ dinv,
                                                 const int* __restrict__ rp,
                                                 const int* __restrict__ pos,
                                                 int2* __restrict__ cvp) {
    int e = blockIdx.x * 256 + threadIdx.x;
    if (e < EE) {
        int s = src[e], d = dst[e];
        int p = rp[d] + pos[e];
        int2 cv;
        cv.x = s;
        cv.y = __float_as_int(dinv[s] * w[e] * dinv[d]);
        cvp[p] = cv;
    }
}

// ---------------- MFMA epilogue: LDS transpose -> coalesced us8 stores ----------------
// tb row stride 136 shorts (272 B): 2B writes land 2-way max; us8 reads 16B-aligned.

#define MM_EPILOGUE_128(H_)                                                  \
    {                                                                        \
        _Pragma("unroll")                                                    \
        for (int n = 0; n < 8; ++n) {                                        \
            _Pragma("unroll")                                                \
            for (int v = 0; v < 4; ++v)                                      \
                tb[wid][g * 4 + v][n * 16 + sl] = f2b(acc[n][v]);            \
        }                                                                    \
        __syncthreads();                                                     \
        _Pragma("unroll")                                                    \
        for (int c4 = 0; c4 < 4; ++c4) {                                     \
            int chunk = c4 * 64 + lane;                                      \
            int row = chunk >> 4, seg = chunk & 15;                          \
            int grow = r0 + row;                                             \
            if (grow < NN)                                                   \
                *(us8*)(H_ + (size_t)grow * DD + seg * 8) =                  \
                    *(const us8*)(&tb[wid][row][seg * 8]);                   \
        }                                                                    \
    }

// ---------------- fused mm0: fp32 x -> (Abf, H = x @ W0) ----------------
__global__ __launch_bounds__(256) void k_mmx(const float* __restrict__ x,
                                             const unsigned short* __restrict__ WT,
                                             unsigned short* __restrict__ Abf,
                                             unsigned short* __restrict__ H) {
    __shared__ unsigned short tb[4][16][136];
    int wid = threadIdx.x >> 6;
    int lane = threadIdx.x & 63;
    int r0 = blockIdx.x * 64 + wid * 16;
    int sl = lane & 15, g = lane >> 4;
    int arow = r0 + sl;
    bool avalid = arow < NN;
    if (!avalid) arow = NN - 1;

    f32x4 acc[8];
    #pragma unroll
    for (int n = 0; n < 8; ++n) acc[n] = (f32x4){0.f, 0.f, 0.f, 0.f};

    const float* xrow = x + (size_t)arow * DD;
    #pragma unroll
    for (int kc = 0; kc < 4; ++kc) {
        int chunk = kc * 4 + g;
        float4 lo = *(const float4*)(xrow + chunk * 8);
        float4 hi = *(const float4*)(xrow + chunk * 8 + 4);
        us8 r;
        r[0] = f2b(lo.x); r[1] = f2b(lo.y); r[2] = f2b(lo.z); r[3] = f2b(lo.w);
        r[4] = f2b(hi.x); r[5] = f2b(hi.y); r[6] = f2b(hi.z); r[7] = f2b(hi.w);
        if (avalid) ((us8*)(Abf + (size_t)arow * DD))[chunk] = r;
        bf16x8 a = *(bf16x8*)&r;
        #pragma unroll
        for (int n = 0; n < 8; ++n) {
            const bf16x8* wrow = (const bf16x8*)(WT + (size_t)(n * 16 + sl) * DD);
            bf16x8 b = wrow[kc * 4 + g];
            acc[n] = __builtin_amdgcn_mfma_f32_16x16x32_bf16(a, b, acc[n], 0, 0, 0);
        }
    }
    MM_EPILOGUE_128(H);
}

// ---------------- bf16 MFMA matmul: H[N,128] = X[N,128] @ W ----------------
__global__ __launch_bounds__(256) void k_mm_mfma(const unsigned short* __restrict__ X,
                                                 const unsigned short* __restrict__ WT,
                                                 unsigned short* __restrict__ H) {
    __shared__ unsigned short tb[4][16][136];
    int wid = threadIdx.x >> 6;
    int lane = threadIdx.x & 63;
    int r0 = blockIdx.x * 64 + wid * 16;
    int sl = lane & 15, g = lane >> 4;
    int arow = r0 + sl;
    if (arow >= NN) arow = NN - 1;

    f32x4 acc[8];
    #pragma unroll
    for (int n = 0; n < 8; ++n) acc[n] = (f32x4){0.f, 0.f, 0.f, 0.f};

    const bf16x8* xrow = (const bf16x8*)(X + (size_t)arow * DD);
    #pragma unroll
    for (int kc = 0; kc < 4; ++kc) {
        bf16x8 a = xrow[kc * 4 + g];
        #pragma unroll
        for (int n = 0; n < 8; ++n) {
            const bf16x8* wrow = (const bf16x8*)(WT + (size_t)(n * 16 + sl) * DD);
            bf16x8 b = wrow[kc * 4 + g];
            acc[n] = __builtin_amdgcn_mfma_f32_16x16x32_bf16(a, b, acc[n], 0, 0, 0);
        }
    }
    MM_EPILOGUE_128(H);
}

__global__ __launch_bounds__(256) void k_mm40b(const unsigned short* __restrict__ X,
                                               const unsigned short* __restrict__ WfT,
                                               unsigned short* __restrict__ H) {
    int wid = threadIdx.x >> 6;
    int lane = threadIdx.x & 63;
    int r0 = blockIdx.x * 64 + wid * 16;
    int sl = lane & 15, g = lane >> 4;
    int arow = r0 + sl;
    if (arow >= NN) arow = NN - 1;

    f32x4 acc[4];
    #pragma unroll
    for (int n = 0; n < 4; ++n) acc[n] = (f32x4){0.f, 0.f, 0.f, 0.f};

    const bf16x8* xrow = (const bf16x8*)(X + (size_t)arow * DD);
    #pragma unroll
    for (int kc = 0; kc < 4; ++kc) {
        bf16x8 a = xrow[kc * 4 + g];
        #pragma unroll
        for (int n = 0; n < 4; ++n) {
            const bf16x8* wrow = (const bf16x8*)(WfT + (size_t)(n * 16 + sl) * DD);
            bf16x8 b = wrow[kc * 4 + g];
            acc[n] = __builtin_amdgcn_mfma_f32_16x16x32_bf16(a, b, acc[n], 0, 0, 0);
        }
    }
    #pragma unroll
    for (int n = 0; n < 4; ++n) {
        #pragma unroll
        for (int v = 0; v < 4; ++v) {
            int row = r0 + g * 4 + v;
            if (row < NN) H[(size_t)row * 64 + n * 16 + sl] = f2b(acc[n][v]);
        }
    }
}

// ---------------- aggregation core (4-way unroll, packed col/val) ----------------

#define AGG_CORE(h_, node_, sl_, a_, STRIDE_)                               \
    {                                                                       \
        float dv = dinv[node_];                                             \
        float dv2 = dv * dv;                                                \
        us8 m_ = ((const us8*)(h_ + (size_t)node_ * STRIDE_))[sl_];         \
        _Pragma("unroll")                                                   \
        for (int j = 0; j < 8; ++j) a_[j] = dv2 * b2f(m_[j]);               \
        int e = rp[node_], end = rp[node_ + 1];                             \
        for (; e + 4 <= end; e += 4) {                                      \
            int2 c0 = cvp[e], c1 = cvp[e + 1], c2 = cvp[e + 2], c3 = cvp[e + 3]; \
            us8 q0 = ((const us8*)(h_ + (size_t)c0.x * STRIDE_))[sl_];      \
            us8 q1 = ((const us8*)(h_ + (size_t)c1.x * STRIDE_))[sl_];      \
            us8 q2 = ((const us8*)(h_ + (size_t)c2.x * STRIDE_))[sl_];      \
            us8 q3 = ((const us8*)(h_ + (size_t)c3.x * STRIDE_))[sl_];      \
            float v0 = __int_as_float(c0.y), v1 = __int_as_float(c1.y);     \
            float v2 = __int_as_float(c2.y), v3 = __int_as_float(c3.y);     \
            _Pragma("unroll")                                               \
            for (int j = 0; j < 8; ++j)                                     \
                a_[j] += (v0 * b2f(q0[j]) + v1 * b2f(q1[j]))                \
                       + (v2 * b2f(q2[j]) + v3 * b2f(q3[j]));               \
        }                                                                   \
        for (; e < end; ++e) {                                              \
            int2 c0 = cvp[e];                                               \
            us8 q0 = ((const us8*)(h_ + (size_t)c0.x * STRIDE_))[sl_];      \
            float v0 = __int_as_float(c0.y);                                \
            _Pragma("unroll")                                               \
            for (int j = 0; j < 8; ++j) a_[j] += v0 * b2f(q0[j]);           \
        }                                                                   \
    }

__global__ __launch_bounds__(256) void k_agg128(const unsigned short* __restrict__ h,
                                                const float* __restrict__ dinv,
                                                const int* __restrict__ rp,
                                                const int2* __restrict__ cvp,
                                                const float* __restrict__ bias,
                                                unsigned short* __restrict__ outb) {
    int node = blockIdx.x * 16 + (threadIdx.x >> 4);
    int sl = threadIdx.x & 15;
    if (node >= NN) return;
    float a[8];
    AGG_CORE(h, node, sl, a, DD);
    float4 bz0 = ((const float4*)bias)[sl * 2];
    float4 bz1 = ((const float4*)bias)[sl * 2 + 1];
    float bb[8] = {bz0.x, bz0.y, bz0.z, bz0.w, bz1.x, bz1.y, bz1.z, bz1.w};
    us8 r;
    #pragma unroll
    for (int j = 0; j < 8; ++j) r[j] = f2b(fmaxf(a[j] + bb[j], 0.f));
    ((us8*)(outb + (size_t)node * DD))[sl] = r;
}

__global__ __launch_bounds__(256) void k_agg128_nr(const unsigned short* __restrict__ h,
                                                   const float* __restrict__ dinv,
                                                   const int* __restrict__ rp,
                                                   const int2* __restrict__ cvp,
                                                   const float* __restrict__ bias,
                                                   unsigned short* __restrict__ Abf) {
    int node = blockIdx.x * 16 + (threadIdx.x >> 4);
    int sl = threadIdx.x & 15;
    if (node >= NN) return;
    float a[8];
    AGG_CORE(h, node, sl, a, DD);
    float4 bz0 = ((const float4*)bias)[sl * 2];
    float4 bz1 = ((const float4*)bias)[sl * 2 + 1];
    float bb[8] = {bz0.x, bz0.y, bz0.z, bz0.w, bz1.x, bz1.y, bz1.z, bz1.w};
    float ss = 0.f;
    #pragma unroll
    for (int j = 0; j < 8; ++j) {
        a[j] = fmaxf(a[j] + bb[j], 0.f);
        ss += a[j] * a[j];
    }
    ss += __shfl_xor(ss, 1);
    ss += __shfl_xor(ss, 2);
    ss += __shfl_xor(ss, 4);
    ss += __shfl_xor(ss, 8);
    float sc = 1.0f / fmaxf(sqrtf(ss), 1e-12f);
    us8 oldb = ((const us8*)(Abf + (size_t)node * DD))[sl];
    us8 rb;
    #pragma unroll
    for (int j = 0; j < 8; ++j)
        rb[j] = f2b((a[j] * sc + b2f(oldb[j])) * 0.5f);
    ((us8*)(Abf + (size_t)node * DD))[sl] = rb;
}

__global__ __launch_bounds__(256) void k_agg_final(const unsigned short* __restrict__ h,
                                                   const float* __restrict__ dinv,
                                                   const int* __restrict__ rp,
                                                   const int2* __restrict__ cvp,
                                                   const float* __restrict__ bias,
                                                   float* __restrict__ out) {
    int node = blockIdx.x * 32 + (threadIdx.x >> 3);
    int sl = threadIdx.x & 7;
    if (node >= NN) return;
    float a[8];
    AGG_CORE(h, node, sl, a, 64);
    bool real = sl < 5;
    float vv[8];
    if (real) {
        float4 bz0 = ((const float4*)bias)[sl * 2];
        float4 bz1 = ((const float4*)bias)[sl * 2 + 1];
        float bb[8] = {bz0.x, bz0.y, bz0.z, bz0.w, bz1.x, bz1.y, bz1.z, bz1.w};
        #pragma unroll
        for (int j = 0; j < 8; ++j) vv[j] = a[j] + bb[j];
    } else {
        #pragma unroll
        for (int j = 0; j < 8; ++j) vv[j] = -3.0e38f;
    }
    float m = vv[0];
    #pragma unroll
    for (int j = 1; j < 8; ++j) m = fmaxf(m, vv[j]);
    m = fmaxf(m, __shfl_xor(m, 1));
    m = fmaxf(m, __shfl_xor(m, 2));
    m = fmaxf(m, __shfl_xor(m, 4));
    float s = 0.f;
    if (real) {
        #pragma unroll
        for (int j = 0; j < 8; ++j) s += expf(vv[j] - m);
    }
    s += __shfl_xor(s, 1);
    s += __shfl_xor(s, 2);
    s += __shfl_xor(s, 4);
    float ls = m + logf(s);
    if (real) {
        float4 o0 = {vv[0] - ls, vv[1] - ls, vv[2] - ls, vv[3] - ls};
        float4 o1 = {vv[4] - ls, vv[5] - ls, vv[6] - ls, vv[7] - ls};
        float* orow = out + (size_t)node * CC + sl * 8;
        *(float4*)(orow) = o0;
        *(float4*)(orow + 4) = o1;
    }
}

// ---------------- launch ----------------

extern "C" void kernel_launch(void* const* d_in, const int* in_sizes, int n_in,
                              void* d_out, int out_size, void* d_ws, size_t ws_size,
                              hipStream_t stream) {
    const float* x  = (const float*)d_in[0];
    const int*   ei = (const int*)d_in[1];
    const float* ew = (const float*)d_in[2];
    const float* Wb = (const float*)d_in[3];
    const float* bb = (const float*)d_in[4];
    const float* Wf = (const float*)d_in[5];
    const float* bf_ = (const float*)d_in[6];
    const int* src = ei;
    const int* dst = ei + EE;
    float* out = (float*)d_out;

    char* p = (char*)d_ws;
    unsigned short*     Abf    = (unsigned short*)p;     p += (size_t)NN * DD * 2;
    unsigned short*     Bbf    = (unsigned short*)p;     p += (size_t)NN * DD * 2;
    unsigned short*     Cbf    = (unsigned short*)p;     p += (size_t)NN * DD * 2;
    unsigned short*     H48    = (unsigned short*)p;     p += (size_t)NN * 64 * 2;
    unsigned short*     WT     = (unsigned short*)p;     p += (size_t)8 * DD * DD * 2;
    unsigned short*     WfT    = (unsigned short*)p;     p += (size_t)64 * DD * 2;
    unsigned long long* degcnt = (unsigned long long*)p; p += (size_t)NN * 8;
    float* dinv = (float*)p; p += (size_t)NN * 4;
    int*   rp   = (int*)p;   p += (size_t)(NN + 1) * 4;
    int*   pos  = (int*)p;   p += (size_t)EE * 4;
    int2*  cvp  = (int2*)p;  p += (size_t)EE * 8;
    int*   partial = (int*)p; p += 128 * 4;

    hipMemsetAsync(degcnt, 0, (size_t)NN * 8, stream);

    k_edge1<<<(EE + 255) / 256, 256, 0, stream>>>(dst, ew, degcnt, pos);
    k_scan1p<<<98 + (8 * DD * DD + 64 * DD + 255) / 256, 256, 0, stream>>>(
        degcnt, dinv, rp, partial, Wb, Wf, WT, WfT);
    k_scan3<<<(NN + 255) / 256, 256, 0, stream>>>(rp, partial);
    k_scatter<<<(EE + 255) / 256, 256, 0, stream>>>(src, dst, ew, dinv, rp, pos, cvp);

    int gb = (NN + 63) / 64;
    k_mmx<<<gb, 256, 0, stream>>>(x, WT, Abf, Bbf);
    for (int blk = 0; blk < 4; ++blk) {
        k_agg128<<<(NN + 15) / 16, 256, 0, stream>>>(Bbf, dinv, rp, cvp,
                                                     bb + (size_t)(2 * blk) * DD, Cbf);
        k_mm_mfma<<<gb, 256, 0, stream>>>(Cbf, WT + (size_t)(2 * blk + 1) * DD * DD, Bbf);
        k_agg128_nr<<<(NN + 15) / 16, 256, 0, stream>>>(Bbf, dinv, rp, cvp,
                                                        bb + (size_t)(2 * blk + 1) * DD, Abf);
        if (blk < 3)
            k_mm_mfma<<<gb, 256, 0, stream>>>(Abf, WT + (size_t)(2 * blk + 2) * DD * DD, Bbf);
    }
    k_mm40b<<<gb, 256, 0, stream>>>(Abf, WfT, H48);
    k_agg_final<<<(NN + 31) / 32, 256, 0, stream>>>(H48, dinv, rp, cvp, bf_, out);
}